// Round 1
// baseline (280.996 us; speedup 1.0000x reference)
//
#include <hip/hip_runtime.h>
#include <math.h>

// Problem dims (fixed by setup_inputs)
#define BB    8
#define TT    4096
#define II    64
#define DD    128
#define OO    64
#define PP    8
#define NTOT  (BB * TT)        // 32768
#define CT    64               // t-chunk for scan
#define NC    (TT / CT)        // 64 chunks per batch

// ---------------------------------------------------------------------------
// Kernel A: h_bar[n,d] = sum_i interp(x[n,i]; hv[i,:,d])
//           z[n,d]    = sigmoid(sum_i interp(x[n,i]; zv[i,:,d]))
// one block per n, 128 threads (one per d)
// ---------------------------------------------------------------------------
__global__ __launch_bounds__(128) void apl_hz_kernel(
    const float* __restrict__ x,    // (N, 64)
    const float* __restrict__ hv,   // (64, 8, 128)
    const float* __restrict__ zv,   // (64, 8, 128)
    float* __restrict__ h_bar,      // (N, 128)  -> d_out ht region
    float* __restrict__ z_out)      // (N, 128)  -> ws
{
    __shared__ float sw0[II];
    __shared__ float sw1[II];
    __shared__ int   sidx[II];

    const int n   = blockIdx.x;
    const int tid = threadIdx.x;

    if (tid < II) {
        float xv = x[(size_t)n * II + tid];
        float t  = (xv + 1.0f) * 3.5f;          // (x - lo)/(hi-lo)*(P-1)
        t = fminf(fmaxf(t, 0.0f), 7.0f);
        int idx = (int)t;                        // floor (t >= 0)
        if (idx > PP - 2) idx = PP - 2;
        float frac = t - (float)idx;
        sidx[tid] = idx;
        sw0[tid]  = 1.0f - frac;
        sw1[tid]  = frac;
    }
    __syncthreads();

    const int d = tid;  // 0..127
    float acc_h = 0.0f;
    float acc_z = 0.0f;
    #pragma unroll 8
    for (int i = 0; i < II; ++i) {
        const int base = (i * PP + sidx[i]) * DD + d;
        const float w0 = sw0[i];
        const float w1 = sw1[i];
        acc_h = fmaf(w0, hv[base], acc_h);
        acc_h = fmaf(w1, hv[base + DD], acc_h);
        acc_z = fmaf(w0, zv[base], acc_z);
        acc_z = fmaf(w1, zv[base + DD], acc_z);
    }
    const size_t o = (size_t)n * DD + d;
    h_bar[o] = acc_h;
    z_out[o] = 1.0f / (1.0f + expf(-acc_z));
}

// ---------------------------------------------------------------------------
// Scan phase 1: per (b, chunk): partial[b,c,d] = sum over chunk of h_bar
// ---------------------------------------------------------------------------
__global__ __launch_bounds__(128) void scan_partial_kernel(
    const float* __restrict__ h_bar,   // (B, T, 128)
    float* __restrict__ partial)       // (B, NC, 128)
{
    const int b = blockIdx.x / NC;
    const int c = blockIdx.x % NC;
    const int d = threadIdx.x;
    const float* p = h_bar + ((size_t)b * TT + (size_t)c * CT) * DD + d;
    float s = 0.0f;
    #pragma unroll 8
    for (int t = 0; t < CT; ++t) s += p[(size_t)t * DD];
    partial[((size_t)b * NC + c) * DD + d] = s;
}

// ---------------------------------------------------------------------------
// Scan phase 2: exclusive scan of chunk partials + h0 offset
// one block per b, 128 threads (d); serial over NC chunks
// ---------------------------------------------------------------------------
__global__ __launch_bounds__(128) void scan_exclusive_kernel(
    float* __restrict__ partial,        // (B, NC, 128), in place
    const float* __restrict__ h0)       // (B, 128)
{
    const int b = blockIdx.x;
    const int d = threadIdx.x;
    float run = h0[(size_t)b * DD + d];
    for (int c = 0; c < NC; ++c) {
        const size_t o = ((size_t)b * NC + c) * DD + d;
        float v = partial[o];
        partial[o] = run;
        run += v;
    }
}

// ---------------------------------------------------------------------------
// Scan phase 3: ht = (1-z)*(running cumsum + h0) + z*h_bar, in place over h_bar
// ---------------------------------------------------------------------------
__global__ __launch_bounds__(128) void scan_apply_kernel(
    const float* __restrict__ z,        // (B, T, 128)
    float* __restrict__ hbar_ht,        // (B, T, 128) in: h_bar, out: ht
    const float* __restrict__ partial)  // (B, NC, 128) exclusive sums
{
    const int b = blockIdx.x / NC;
    const int c = blockIdx.x % NC;
    const int d = threadIdx.x;
    const size_t base = ((size_t)b * TT + (size_t)c * CT) * DD + d;
    float run = partial[((size_t)b * NC + c) * DD + d];
    #pragma unroll 4
    for (int t = 0; t < CT; ++t) {
        const size_t o = base + (size_t)t * DD;
        const float hb = hbar_ht[o];
        const float zt = z[o];
        run += hb;
        hbar_ht[o] = (1.0f - zt) * run + zt * hb;
    }
}

// ---------------------------------------------------------------------------
// Kernel C: y[n,o] = sum_d interp(ht[n,d]; ov[d,:,o])
// one block per n, 64 threads (one per o)
// ---------------------------------------------------------------------------
__global__ __launch_bounds__(64) void apl_out_kernel(
    const float* __restrict__ ht,   // (N, 128)
    const float* __restrict__ ov,   // (128, 8, 64)
    float* __restrict__ y)          // (N, 64)
{
    __shared__ float sw0[DD];
    __shared__ float sw1[DD];
    __shared__ int   sidx[DD];

    const int n   = blockIdx.x;
    const int tid = threadIdx.x;

    for (int d = tid; d < DD; d += 64) {
        float hval = ht[(size_t)n * DD + d];
        float t = (hval + 1.0f) * 3.5f;
        t = fminf(fmaxf(t, 0.0f), 7.0f);
        int idx = (int)t;
        if (idx > PP - 2) idx = PP - 2;
        float frac = t - (float)idx;
        sidx[d] = idx;
        sw0[d]  = 1.0f - frac;
        sw1[d]  = frac;
    }
    __syncthreads();

    float acc = 0.0f;
    #pragma unroll 8
    for (int d = 0; d < DD; ++d) {
        const int base = (d * PP + sidx[d]) * OO + tid;
        acc = fmaf(sw0[d], ov[base], acc);
        acc = fmaf(sw1[d], ov[base + OO], acc);
    }
    y[(size_t)n * OO + tid] = acc;
}

// ---------------------------------------------------------------------------
extern "C" void kernel_launch(void* const* d_in, const int* in_sizes, int n_in,
                              void* d_out, int out_size, void* d_ws, size_t ws_size,
                              hipStream_t stream) {
    const float* x  = (const float*)d_in[0];   // (B,T,I)
    const float* h0 = (const float*)d_in[1];   // (B,D)
    const float* zv = (const float*)d_in[2];   // (I,P,D)
    const float* hv = (const float*)d_in[3];   // (I,P,D)
    const float* ov = (const float*)d_in[4];   // (D,P,O)

    float* y  = (float*)d_out;                              // (B,T,O)
    float* ht = (float*)d_out + (size_t)NTOT * OO;          // (B,T,D)

    float* z_buf   = (float*)d_ws;                          // (B,T,D)  16 MB
    float* partial = z_buf + (size_t)NTOT * DD;             // (B,NC,D) 256 KB

    // 1) h_bar (into ht region) and z (into ws)
    apl_hz_kernel<<<NTOT, 128, 0, stream>>>(x, hv, zv, ht, z_buf);
    // 2) chunked scan over t
    scan_partial_kernel<<<BB * NC, 128, 0, stream>>>(ht, partial);
    scan_exclusive_kernel<<<BB, 128, 0, stream>>>(partial, h0);
    scan_apply_kernel<<<BB * NC, 128, 0, stream>>>(z_buf, ht, partial);
    // 3) output APL
    apl_out_kernel<<<NTOT, 64, 0, stream>>>(ht, ov, y);
}

// Round 2
// 132.076 us; speedup vs baseline: 2.1275x; 2.1275x over previous
//
#include <hip/hip_runtime.h>
#include <math.h>

// Problem dims (fixed by setup_inputs)
#define BBATCH 8
#define TT    4096
#define II    64
#define DD    128
#define OO    64
#define PP    8
#define NTOT  (BBATCH * TT)      // 32768
#define CT    64                 // t-chunk for scan
#define NC    (TT / CT)          // 64 chunks per batch

typedef short bf16x8 __attribute__((ext_vector_type(8)));
typedef float f32x4  __attribute__((ext_vector_type(4)));

__device__ __forceinline__ unsigned short f2bf(float f) {
    union { float f; unsigned int u; } v; v.f = f;
    unsigned int r = v.u + 0x7fffu + ((v.u >> 16) & 1u);   // RNE
    return (unsigned short)(r >> 16);
}

__device__ __forceinline__ void gload_lds16(const void* g, void* l) {
    __builtin_amdgcn_global_load_lds(
        (const __attribute__((address_space(1))) unsigned int*)g,
        (__attribute__((address_space(3))) unsigned int*)l, 16, 0, 0);
}

// ---------------------------------------------------------------------------
// prep_tables: Vt[col][k] bf16 (256x512) from hv|zv (k=i*8+p, col = d or 128+d)
//              Ot[col][k] bf16 (64x1024) from ov (k=d*8+p)
// ---------------------------------------------------------------------------
__global__ __launch_bounds__(256) void prep_tables(
    const float* __restrict__ hv, const float* __restrict__ zv,
    const float* __restrict__ ov,
    unsigned short* __restrict__ Vt, unsigned short* __restrict__ Ot)
{
    const int b = blockIdx.x, tid = threadIdx.x;
    if (b < 512) {                 // Vt: k = b, col = tid
        const int k = b, c = tid;
        float v = (c < 128) ? hv[(size_t)k * 128 + c] : zv[(size_t)k * 128 + (c - 128)];
        Vt[(size_t)c * 512 + k] = f2bf(v);
    } else {                       // Ot: k = (b-512)*4 + tid>>6, col = tid&63
        const int k = (b - 512) * 4 + (tid >> 6), c = tid & 63;
        Ot[(size_t)c * 1024 + k] = f2bf(ov[(size_t)k * 64 + c]);
    }
}

// ---------------------------------------------------------------------------
// APL1 GEMM: C(n, 0..255) = W(n, 0..511) x Vt^T ; cols 0-127 -> h_bar,
// 128-255 -> sigmoid -> z.  BM=32, K=512, Kc=32 (16 chunks, dbuf), 4 waves,
// wave-tile 32x64 (2x4 tiles of 16x16x32 MFMA).
// LDS: W 32x1024B swizzled (u^=r&7) | Vt bufs 2 x (256 rows x 64B, u^=(r>>2)&3)
// ---------------------------------------------------------------------------
__global__ __launch_bounds__(256) void apl1_gemm(
    const float* __restrict__ x, const unsigned short* __restrict__ Vt,
    float* __restrict__ h_bar, float* __restrict__ z_out)
{
    __shared__ unsigned char smem[65536];
    const int tid = threadIdx.x;
    const int wave = tid >> 6, lane = tid & 63;
    const int n0 = blockIdx.x * 32;

    // stage Vt chunk 0 into buf0 (16 KB, 16 wave-instrs of 1KB)
    {
        unsigned char* buf = smem + 32768;
        for (int j = 0; j < 4; ++j) {
            const int r0 = wave * 64 + j * 16;
            const int r = r0 + (lane >> 2);
            const int ug = (lane & 3) ^ ((r >> 2) & 3);
            gload_lds16((const unsigned char*)Vt + (size_t)r * 1024 + ug * 16,
                        buf + r0 * 64);
        }
    }

    // build W (32 rows x 512 k) in LDS: pair (n=wave+4*it, i=lane)
    for (int it = 0; it < 8; ++it) {
        const int n = wave + 4 * it;
        const int i = lane;
        float xv = x[(size_t)(n0 + n) * II + i];
        float t = fminf(fmaxf((xv + 1.0f) * 3.5f, 0.0f), 7.0f);
        int idx = (int)t; if (idx > 6) idx = 6;
        float frac = t - (float)idx;
        const unsigned int b0 = f2bf(1.0f - frac);
        const unsigned int b1 = f2bf(frac);
        const int q = idx >> 1;
        const bool odd = (idx & 1) != 0;
        const unsigned int vA = odd ? (b0 << 16) : (b0 | (b1 << 16));
        const unsigned int vB = odd ? b1 : 0u;
        unsigned int w0 = (q == 0) ? vA : 0u;
        unsigned int w1 = (q == 1) ? vA : ((q == 0) ? vB : 0u);
        unsigned int w2 = (q == 2) ? vA : ((q == 1) ? vB : 0u);
        unsigned int w3 = (q == 3) ? vA : ((q == 2) ? vB : 0u);
        const int up = i ^ (n & 7);
        *(uint4*)(smem + n * 1024 + up * 16) = make_uint4(w0, w1, w2, w3);
    }
    __syncthreads();

    const int colbase = wave * 64;
    f32x4 acc[2][4];
    for (int tr = 0; tr < 2; ++tr)
        for (int tc = 0; tc < 4; ++tc)
            acc[tr][tc] = (f32x4){0.f, 0.f, 0.f, 0.f};

    const int klane = (lane >> 4) * 8;   // 0,8,16,24

    for (int c = 0; c < 16; ++c) {
        unsigned char* cur = smem + 32768 + (c & 1) * 16384;
        if (c < 15) {
            unsigned char* nxt = smem + 32768 + ((c + 1) & 1) * 16384;
            for (int j = 0; j < 4; ++j) {
                const int r0 = wave * 64 + j * 16;
                const int r = r0 + (lane >> 2);
                const int ug = (lane & 3) ^ ((r >> 2) & 3);
                gload_lds16((const unsigned char*)Vt + (size_t)r * 1024 + (c + 1) * 64 + ug * 16,
                            nxt + r0 * 64);
            }
        }
        bf16x8 a[2];
        const int ugA = (c * 32 + klane) >> 3;
        for (int tr = 0; tr < 2; ++tr) {
            const int r = tr * 16 + (lane & 15);
            a[tr] = *(const bf16x8*)(smem + r * 1024 + (ugA ^ (r & 7)) * 16);
        }
        bf16x8 b[4];
        const int ugB = klane >> 3;      // 0..3
        for (int tc = 0; tc < 4; ++tc) {
            const int rc = colbase + tc * 16 + (lane & 15);
            b[tc] = *(const bf16x8*)(cur + rc * 64 + (ugB ^ ((rc >> 2) & 3)) * 16);
        }
        for (int tr = 0; tr < 2; ++tr)
            for (int tc = 0; tc < 4; ++tc)
                acc[tr][tc] = __builtin_amdgcn_mfma_f32_16x16x32_bf16(a[tr], b[tc], acc[tr][tc], 0, 0, 0);
        __syncthreads();
    }

    // epilogue: C/D layout col=lane&15, row=(lane>>4)*4+reg
    for (int tr = 0; tr < 2; ++tr) {
        for (int tc = 0; tc < 4; ++tc) {
            const int col = colbase + tc * 16 + (lane & 15);
            const int n = n0 + tr * 16 + (lane >> 4) * 4;
            f32x4 v = acc[tr][tc];
            if (col < 128) {
                for (int rg = 0; rg < 4; ++rg)
                    h_bar[(size_t)(n + rg) * DD + col] = v[rg];
            } else {
                const int zc = col - 128;
                for (int rg = 0; rg < 4; ++rg)
                    z_out[(size_t)(n + rg) * DD + zc] = 1.0f / (1.0f + __expf(-v[rg]));
            }
        }
    }
}

// ---------------------------------------------------------------------------
// APL2 GEMM: y(n, 0..63) = W2(n, 0..1023) x Ot^T.  BM=128, Kc=64 (16 chunks,
// W rebuilt per chunk from ht, both dbuf), 4 waves 2x2, wave-tile 64x32.
// LDS: W bufs 2 x (128 rows x 128B) at 0 | Ot bufs 2 x (64 rows x 128B) at 32768
// ---------------------------------------------------------------------------
__global__ __launch_bounds__(256) void apl2_gemm(
    const float* __restrict__ ht, const unsigned short* __restrict__ Ot,
    float* __restrict__ y)
{
    __shared__ unsigned char smem[49152];
    const int tid = threadIdx.x;
    const int wave = tid >> 6, lane = tid & 63;
    const int n0 = blockIdx.x * 128;
    const int wr = wave >> 1, wc = wave & 1;

    // helpers ------------------------------------------------------------
    auto stageOt = [&](int c, unsigned char* buf) {
        for (int j = 0; j < 2; ++j) {
            const int r0 = wave * 16 + j * 8;
            const int r = r0 + (lane >> 3);
            const int ug = (lane & 7) ^ (r & 7);
            gload_lds16((const unsigned char*)Ot + (size_t)r * 2048 + c * 128 + ug * 16,
                        buf + r0 * 128);
        }
    };
    auto buildW = [&](int c, unsigned char* buf, const float* htv) {
        for (int it = 0; it < 4; ++it) {
            const int n = (tid >> 3) + 32 * it;
            const int dl = tid & 7;
            float t = fminf(fmaxf((htv[it] + 1.0f) * 3.5f, 0.0f), 7.0f);
            int idx = (int)t; if (idx > 6) idx = 6;
            float frac = t - (float)idx;
            const unsigned int b0 = f2bf(1.0f - frac);
            const unsigned int b1 = f2bf(frac);
            const int q = idx >> 1;
            const bool odd = (idx & 1) != 0;
            const unsigned int vA = odd ? (b0 << 16) : (b0 | (b1 << 16));
            const unsigned int vB = odd ? b1 : 0u;
            unsigned int w0 = (q == 0) ? vA : 0u;
            unsigned int w1 = (q == 1) ? vA : ((q == 0) ? vB : 0u);
            unsigned int w2 = (q == 2) ? vA : ((q == 1) ? vB : 0u);
            unsigned int w3 = (q == 3) ? vA : ((q == 2) ? vB : 0u);
            const int up = dl ^ (n & 7);
            *(uint4*)(buf + n * 128 + up * 16) = make_uint4(w0, w1, w2, w3);
        }
    };
    auto loadHt = [&](int c, float* htv) {
        for (int it = 0; it < 4; ++it) {
            const int n = (tid >> 3) + 32 * it;
            const int dl = tid & 7;
            htv[it] = ht[(size_t)(n0 + n) * DD + c * 8 + dl];
        }
    };

    // prologue
    float htv[4];
    stageOt(0, smem + 32768);
    loadHt(0, htv);
    buildW(0, smem, htv);
    __syncthreads();

    f32x4 acc[4][2];
    for (int tr = 0; tr < 4; ++tr)
        for (int tc = 0; tc < 2; ++tc)
            acc[tr][tc] = (f32x4){0.f, 0.f, 0.f, 0.f};

    const int klane = (lane >> 4) * 8;

    for (int c = 0; c < 16; ++c) {
        unsigned char* Wcur = smem + (c & 1) * 16384;
        unsigned char* Ocur = smem + 32768 + (c & 1) * 8192;
        if (c < 15) {
            stageOt(c + 1, smem + 32768 + ((c + 1) & 1) * 8192);
            loadHt(c + 1, htv);
        }
        for (int s = 0; s < 2; ++s) {
            const int ug = ((s * 32 + klane) >> 3);   // 0..7
            bf16x8 a[4];
            for (int tr = 0; tr < 4; ++tr) {
                const int r = wr * 64 + tr * 16 + (lane & 15);
                a[tr] = *(const bf16x8*)(Wcur + r * 128 + (ug ^ (r & 7)) * 16);
            }
            bf16x8 b[2];
            for (int tc = 0; tc < 2; ++tc) {
                const int rc = wc * 32 + tc * 16 + (lane & 15);
                b[tc] = *(const bf16x8*)(Ocur + rc * 128 + (ug ^ (rc & 7)) * 16);
            }
            for (int tr = 0; tr < 4; ++tr)
                for (int tc = 0; tc < 2; ++tc)
                    acc[tr][tc] = __builtin_amdgcn_mfma_f32_16x16x32_bf16(a[tr], b[tc], acc[tr][tc], 0, 0, 0);
        }
        if (c < 15)
            buildW(c + 1, smem + ((c + 1) & 1) * 16384, htv);
        __syncthreads();
    }

    for (int tr = 0; tr < 4; ++tr) {
        for (int tc = 0; tc < 2; ++tc) {
            const int col = wc * 32 + tc * 16 + (lane & 15);
            const int n = n0 + wr * 64 + tr * 16 + (lane >> 4) * 4;
            f32x4 v = acc[tr][tc];
            for (int rg = 0; rg < 4; ++rg)
                y[(size_t)(n + rg) * OO + col] = v[rg];
        }
    }
}

// ---------------------------------------------------------------------------
// Scan kernels (unchanged from round 1)
// ---------------------------------------------------------------------------
__global__ __launch_bounds__(128) void scan_partial_kernel(
    const float* __restrict__ h_bar, float* __restrict__ partial)
{
    const int b = blockIdx.x / NC, c = blockIdx.x % NC, d = threadIdx.x;
    const float* p = h_bar + ((size_t)b * TT + (size_t)c * CT) * DD + d;
    float s = 0.0f;
    #pragma unroll 8
    for (int t = 0; t < CT; ++t) s += p[(size_t)t * DD];
    partial[((size_t)b * NC + c) * DD + d] = s;
}

__global__ __launch_bounds__(128) void scan_exclusive_kernel(
    float* __restrict__ partial, const float* __restrict__ h0)
{
    const int b = blockIdx.x, d = threadIdx.x;
    float run = h0[(size_t)b * DD + d];
    for (int c = 0; c < NC; ++c) {
        const size_t o = ((size_t)b * NC + c) * DD + d;
        float v = partial[o];
        partial[o] = run;
        run += v;
    }
}

__global__ __launch_bounds__(128) void scan_apply_kernel(
    const float* __restrict__ z, float* __restrict__ hbar_ht,
    const float* __restrict__ partial)
{
    const int b = blockIdx.x / NC, c = blockIdx.x % NC, d = threadIdx.x;
    const size_t base = ((size_t)b * TT + (size_t)c * CT) * DD + d;
    float run = partial[((size_t)b * NC + c) * DD + d];
    #pragma unroll 4
    for (int t = 0; t < CT; ++t) {
        const size_t o = base + (size_t)t * DD;
        const float hb = hbar_ht[o];
        const float zt = z[o];
        run += hb;
        hbar_ht[o] = (1.0f - zt) * run + zt * hb;
    }
}

// ---------------------------------------------------------------------------
extern "C" void kernel_launch(void* const* d_in, const int* in_sizes, int n_in,
                              void* d_out, int out_size, void* d_ws, size_t ws_size,
                              hipStream_t stream) {
    const float* x  = (const float*)d_in[0];   // (B,T,I)
    const float* h0 = (const float*)d_in[1];   // (B,D)
    const float* zv = (const float*)d_in[2];   // (I,P,D)
    const float* hv = (const float*)d_in[3];   // (I,P,D)
    const float* ov = (const float*)d_in[4];   // (D,P,O)

    float* y  = (float*)d_out;                           // (B,T,O)
    float* ht = (float*)d_out + (size_t)NTOT * OO;       // (B,T,D)

    float* z_buf   = (float*)d_ws;                       // 4M floats, 16 MB
    float* partial = z_buf + (size_t)NTOT * DD;          // 64K floats
    unsigned short* Vt = (unsigned short*)(partial + (size_t)BBATCH * NC * DD); // 256x512
    unsigned short* Ot = Vt + 256 * 512;                                        // 64x1024

    prep_tables<<<768, 256, 0, stream>>>(hv, zv, ov, Vt, Ot);
    apl1_gemm<<<NTOT / 32, 256, 0, stream>>>(x, Vt, ht, z_buf);
    scan_partial_kernel<<<BBATCH * NC, 128, 0, stream>>>(ht, partial);
    scan_exclusive_kernel<<<BBATCH, 128, 0, stream>>>(partial, h0);
    scan_apply_kernel<<<BBATCH * NC, 128, 0, stream>>>(z_buf, ht, partial);
    apl2_gemm<<<NTOT / 128, 256, 0, stream>>>(ht, Ot, y);
}

// Round 3
// 131.614 us; speedup vs baseline: 2.1350x; 1.0035x over previous
//
#include <hip/hip_runtime.h>
#include <math.h>

// Problem dims (fixed by setup_inputs)
#define BBATCH 8
#define TT    4096
#define II    64
#define DD    128
#define OO    64
#define PP    8
#define NTOT  (BBATCH * TT)      // 32768
#define CT    32                 // t-chunk for scan == apl1 block rows
#define NCH   (TT / CT)          // 128 chunks per batch

typedef short bf16x8 __attribute__((ext_vector_type(8)));
typedef float f32x4  __attribute__((ext_vector_type(4)));

__device__ __forceinline__ unsigned short f2bf(float f) {
    union { float f; unsigned int u; } v; v.f = f;
    unsigned int r = v.u + 0x7fffu + ((v.u >> 16) & 1u);   // RNE
    return (unsigned short)(r >> 16);
}

__device__ __forceinline__ float bf2f(unsigned short b) {
    union { float f; unsigned int u; } v; v.u = ((unsigned int)b) << 16;
    return v.f;
}

__device__ __forceinline__ void gload_lds16(const void* g, void* l) {
    __builtin_amdgcn_global_load_lds(
        (const __attribute__((address_space(1))) unsigned int*)g,
        (__attribute__((address_space(3))) unsigned int*)l, 16, 0, 0);
}

// pack the 8 piecewise-linear weights for one (row, input) pair into 4 dwords
__device__ __forceinline__ uint4 apl_w_pack(float xv) {
    float t = fminf(fmaxf((xv + 1.0f) * 3.5f, 0.0f), 7.0f);
    int idx = (int)t; if (idx > 6) idx = 6;
    float frac = t - (float)idx;
    const unsigned int b0 = f2bf(1.0f - frac);
    const unsigned int b1 = f2bf(frac);
    const int q = idx >> 1;
    const bool odd = (idx & 1) != 0;
    const unsigned int vA = odd ? (b0 << 16) : (b0 | (b1 << 16));
    const unsigned int vB = odd ? b1 : 0u;
    uint4 w;
    w.x = (q == 0) ? vA : 0u;
    w.y = (q == 1) ? vA : ((q == 0) ? vB : 0u);
    w.z = (q == 2) ? vA : ((q == 1) ? vB : 0u);
    w.w = (q == 3) ? vA : ((q == 2) ? vB : 0u);
    return w;
}

// ---------------------------------------------------------------------------
// prep_tables: Vt[col][k] bf16 (256x512) from hv|zv (k=i*8+p, col = d or 128+d)
//              Ot[col][k] bf16 (64x1024) from ov (k=d*8+p)
// ---------------------------------------------------------------------------
__global__ __launch_bounds__(256) void prep_tables(
    const float* __restrict__ hv, const float* __restrict__ zv,
    const float* __restrict__ ov,
    unsigned short* __restrict__ Vt, unsigned short* __restrict__ Ot)
{
    const int b = blockIdx.x, tid = threadIdx.x;
    if (b < 512) {                 // Vt: k = b, col = tid
        const int k = b, c = tid;
        float v = (c < 128) ? hv[(size_t)k * 128 + c] : zv[(size_t)k * 128 + (c - 128)];
        Vt[(size_t)c * 512 + k] = f2bf(v);
    } else {                       // Ot: k = (b-512)*4 + tid>>6, col = tid&63
        const int k = (b - 512) * 4 + (tid >> 6), c = tid & 63;
        Ot[(size_t)c * 1024 + k] = f2bf(ov[(size_t)k * 64 + c]);
    }
}

// ---------------------------------------------------------------------------
// APL1 GEMM: C(n, 0..255) = W(n, 0..511) x Vt^T ; cols 0-127 -> h_bar,
// 128-255 -> sigmoid -> z.  BM=32 (== one scan chunk), K=512, Kc=32 (16
// chunks, dbuf), 4 waves, wave-tile 32x64.  Also emits the chunk partial sum
// of h_bar (reduced from MFMA accumulators, no extra memory pass).
// ---------------------------------------------------------------------------
__global__ __launch_bounds__(256) void apl1_gemm(
    const float* __restrict__ x, const unsigned short* __restrict__ Vt,
    float* __restrict__ h_bar, float* __restrict__ z_out,
    float* __restrict__ partial)          // (B*NCH, 128)
{
    __shared__ unsigned char smem[65536];
    const int tid = threadIdx.x;
    const int wave = tid >> 6, lane = tid & 63;
    const int n0 = blockIdx.x * 32;

    // stage Vt chunk 0 into buf0
    {
        unsigned char* buf = smem + 32768;
        for (int j = 0; j < 4; ++j) {
            const int r0 = wave * 64 + j * 16;
            const int r = r0 + (lane >> 2);
            const int ug = (lane & 3) ^ ((r >> 2) & 3);
            gload_lds16((const unsigned char*)Vt + (size_t)r * 1024 + ug * 16,
                        buf + r0 * 64);
        }
    }

    // build W (32 rows x 512 k) in LDS
    for (int it = 0; it < 8; ++it) {
        const int n = wave + 4 * it;
        const int i = lane;
        uint4 w = apl_w_pack(x[(size_t)(n0 + n) * II + i]);
        const int up = i ^ (n & 7);
        *(uint4*)(smem + n * 1024 + up * 16) = w;
    }
    __syncthreads();

    const int colbase = wave * 64;
    f32x4 acc[2][4];
    for (int tr = 0; tr < 2; ++tr)
        for (int tc = 0; tc < 4; ++tc)
            acc[tr][tc] = (f32x4){0.f, 0.f, 0.f, 0.f};

    const int klane = (lane >> 4) * 8;   // 0,8,16,24

    for (int c = 0; c < 16; ++c) {
        unsigned char* cur = smem + 32768 + (c & 1) * 16384;
        if (c < 15) {
            unsigned char* nxt = smem + 32768 + ((c + 1) & 1) * 16384;
            for (int j = 0; j < 4; ++j) {
                const int r0 = wave * 64 + j * 16;
                const int r = r0 + (lane >> 2);
                const int ug = (lane & 3) ^ ((r >> 2) & 3);
                gload_lds16((const unsigned char*)Vt + (size_t)r * 1024 + (c + 1) * 64 + ug * 16,
                            nxt + r0 * 64);
            }
        }
        bf16x8 a[2];
        const int ugA = (c * 32 + klane) >> 3;
        for (int tr = 0; tr < 2; ++tr) {
            const int r = tr * 16 + (lane & 15);
            a[tr] = *(const bf16x8*)(smem + r * 1024 + (ugA ^ (r & 7)) * 16);
        }
        bf16x8 b[4];
        const int ugB = klane >> 3;
        for (int tc = 0; tc < 4; ++tc) {
            const int rc = colbase + tc * 16 + (lane & 15);
            b[tc] = *(const bf16x8*)(cur + rc * 64 + (ugB ^ ((rc >> 2) & 3)) * 16);
        }
        for (int tr = 0; tr < 2; ++tr)
            for (int tc = 0; tc < 4; ++tc)
                acc[tr][tc] = __builtin_amdgcn_mfma_f32_16x16x32_bf16(a[tr], b[tc], acc[tr][tc], 0, 0, 0);
        __syncthreads();
    }

    // chunk partial sums of h_bar (waves 0,1 hold cols 0..127)
    if (wave < 2) {
        for (int tc = 0; tc < 4; ++tc) {
            float s = 0.0f;
            for (int tr = 0; tr < 2; ++tr)
                for (int rg = 0; rg < 4; ++rg)
                    s += acc[tr][tc][rg];
            s += __shfl_xor(s, 16);
            s += __shfl_xor(s, 32);
            if ((lane >> 4) == 0)
                partial[(size_t)blockIdx.x * 128 + colbase + tc * 16 + lane] = s;
        }
    }

    // epilogue: C/D layout col=lane&15, row=(lane>>4)*4+reg
    for (int tr = 0; tr < 2; ++tr) {
        for (int tc = 0; tc < 4; ++tc) {
            const int col = colbase + tc * 16 + (lane & 15);
            const int n = n0 + tr * 16 + (lane >> 4) * 4;
            f32x4 v = acc[tr][tc];
            if (col < 128) {
                for (int rg = 0; rg < 4; ++rg)
                    h_bar[(size_t)(n + rg) * DD + col] = v[rg];
            } else {
                const int zc = col - 128;
                for (int rg = 0; rg < 4; ++rg)
                    z_out[(size_t)(n + rg) * DD + zc] = 1.0f / (1.0f + __expf(-v[rg]));
            }
        }
    }
}

// ---------------------------------------------------------------------------
// Exclusive scan of chunk partials (+h0), one block per batch, LDS-resident.
// ---------------------------------------------------------------------------
__global__ __launch_bounds__(128) void scan_exclusive_v2(
    float* __restrict__ partial, const float* __restrict__ h0)
{
    __shared__ float s[NCH * 128];       // 64 KB
    const int b = blockIdx.x, d = threadIdx.x;
    for (int c = 0; c < NCH; ++c)
        s[c * 128 + d] = partial[((size_t)b * NCH + c) * 128 + d];
    __syncthreads();
    float run = h0[(size_t)b * 128 + d];
    for (int c = 0; c < NCH; ++c) {
        float v = s[c * 128 + d];
        s[c * 128 + d] = run;
        run += v;
    }
    __syncthreads();
    for (int c = 0; c < NCH; ++c)
        partial[((size_t)b * NCH + c) * 128 + d] = s[c * 128 + d];
}

// ---------------------------------------------------------------------------
// Fused: z-mix scan (ht) + output APL GEMM.
// Block = 128 rows (4 chunks).  Phase 1: per-thread serial scan over 64 rows
// (thread = d x seg), writes fp32 ht to d_out and bf16 ht to LDS.
// Phase 2: round-2 apl2 GEMM, W built from LDS ht; Ot double-buffered via
// global_load_lds; single W buffer (2 syncs/chunk).
// ---------------------------------------------------------------------------
__global__ __launch_bounds__(256) void fused_scan_apl2(
    float* hbar_ht,                          // in: h_bar, out: ht (aliased)
    const float* __restrict__ z,
    const float* __restrict__ pexcl,         // (B*NCH, 128) exclusive sums
    const unsigned short* __restrict__ Ot,   // (64, 1024) bf16
    float* __restrict__ y)
{
    __shared__ unsigned short htb[128 * 130];    // 33280 B, padded stride
    __shared__ unsigned char Wbuf[16384];        // 128 rows x 64k x bf16
    __shared__ unsigned char Obuf[2][8192];      // 64 rows x 64k x bf16

    const int tid  = threadIdx.x;
    const int wave = tid >> 6, lane = tid & 63;
    const int n0   = blockIdx.x * 128;
    const int b    = n0 / TT;
    const int cb   = (blockIdx.x & 31) * 4;      // first chunk of this block

    auto stageOt = [&](int c, unsigned char* buf) {
        for (int j = 0; j < 2; ++j) {
            const int r0 = wave * 16 + j * 8;
            const int r = r0 + (lane >> 3);
            const int ug = (lane & 7) ^ (r & 7);
            gload_lds16((const unsigned char*)Ot + (size_t)r * 2048 + c * 128 + ug * 16,
                        buf + r0 * 128);
        }
    };

    // kick off Ot chunk-0 DMA so it overlaps the scan
    stageOt(0, Obuf[0]);

    // ---- phase 1: scan + ht ----
    {
        const int d = tid & 127, seg = tid >> 7;
        float run = pexcl[((size_t)(b * NCH + cb + seg * 2)) * 128 + d];
        const size_t base = (size_t)(n0 + seg * 64) * DD + d;
        #pragma unroll 4
        for (int r = 0; r < 64; ++r) {
            const size_t o = base + (size_t)r * DD;
            float hb = hbar_ht[o];
            float zt = z[o];
            run += hb;
            float htv = (1.0f - zt) * run + zt * hb;
            hbar_ht[o] = htv;
            htb[(seg * 64 + r) * 130 + d] = f2bf(htv);
        }
    }
    __syncthreads();   // htb ready, Ot chunk 0 staged

    auto buildW = [&](int c) {
        #pragma unroll
        for (int it = 0; it < 4; ++it) {
            const int n = (tid >> 3) + 32 * it;
            const int dl = tid & 7;
            float htv = bf2f(htb[n * 130 + c * 8 + dl]);
            uint4 w = apl_w_pack(htv);
            *(uint4*)(Wbuf + n * 128 + (dl ^ (n & 7)) * 16) = w;
        }
    };

    buildW(0);
    __syncthreads();

    const int wr = wave >> 1, wc = wave & 1;
    f32x4 acc[4][2];
    for (int tr = 0; tr < 4; ++tr)
        for (int tc = 0; tc < 2; ++tc)
            acc[tr][tc] = (f32x4){0.f, 0.f, 0.f, 0.f};

    const int klane = (lane >> 4) * 8;

    for (int c = 0; c < 16; ++c) {
        unsigned char* Ocur = Obuf[c & 1];
        if (c < 15)
            stageOt(c + 1, Obuf[(c + 1) & 1]);
        for (int s = 0; s < 2; ++s) {
            const int ug = ((s * 32 + klane) >> 3);
            bf16x8 a[4];
            for (int tr = 0; tr < 4; ++tr) {
                const int r = wr * 64 + tr * 16 + (lane & 15);
                a[tr] = *(const bf16x8*)(Wbuf + r * 128 + (ug ^ (r & 7)) * 16);
            }
            bf16x8 bfr[2];
            for (int tc = 0; tc < 2; ++tc) {
                const int rc = wc * 32 + tc * 16 + (lane & 15);
                bfr[tc] = *(const bf16x8*)(Ocur + rc * 128 + (ug ^ (rc & 7)) * 16);
            }
            for (int tr = 0; tr < 4; ++tr)
                for (int tc = 0; tc < 2; ++tc)
                    acc[tr][tc] = __builtin_amdgcn_mfma_f32_16x16x32_bf16(a[tr], bfr[tc], acc[tr][tc], 0, 0, 0);
        }
        __syncthreads();               // Wbuf consumed by all waves
        if (c < 15) buildW(c + 1);
        __syncthreads();               // Wbuf rebuilt + next Ot staged
    }

    for (int tr = 0; tr < 4; ++tr) {
        for (int tc = 0; tc < 2; ++tc) {
            const int col = wc * 32 + tc * 16 + (lane & 15);
            const int n = n0 + wr * 64 + tr * 16 + (lane >> 4) * 4;
            f32x4 v = acc[tr][tc];
            for (int rg = 0; rg < 4; ++rg)
                y[(size_t)(n + rg) * OO + col] = v[rg];
        }
    }
}

// ---------------------------------------------------------------------------
extern "C" void kernel_launch(void* const* d_in, const int* in_sizes, int n_in,
                              void* d_out, int out_size, void* d_ws, size_t ws_size,
                              hipStream_t stream) {
    const float* x  = (const float*)d_in[0];   // (B,T,I)
    const float* h0 = (const float*)d_in[1];   // (B,D)
    const float* zv = (const float*)d_in[2];   // (I,P,D)
    const float* hv = (const float*)d_in[3];   // (I,P,D)
    const float* ov = (const float*)d_in[4];   // (D,P,O)

    float* y  = (float*)d_out;                           // (B,T,O)
    float* ht = (float*)d_out + (size_t)NTOT * OO;       // (B,T,D)

    float* z_buf   = (float*)d_ws;                       // 4M floats, 16 MB
    float* partial = z_buf + (size_t)NTOT * DD;          // B*NCH*128 = 128K floats
    unsigned short* Vt = (unsigned short*)(partial + (size_t)BBATCH * NCH * 128); // 256x512
    unsigned short* Ot = Vt + 256 * 512;                                          // 64x1024

    prep_tables<<<768, 256, 0, stream>>>(hv, zv, ov, Vt, Ot);
    apl1_gemm<<<NTOT / 32, 256, 0, stream>>>(x, Vt, ht, z_buf, partial);
    scan_exclusive_v2<<<BBATCH, 128, 0, stream>>>(partial, h0);
    fused_scan_apl2<<<NTOT / 128, 256, 0, stream>>>(ht, z_buf, partial, Ot, y);
}

// Round 5
// 127.004 us; speedup vs baseline: 2.2125x; 1.0363x over previous
//
#include <hip/hip_runtime.h>
#include <math.h>

// Problem dims (fixed by setup_inputs)
#define BBATCH 8
#define TT    4096
#define II    64
#define DD    128
#define OO    64
#define PP    8
#define NTOT  (BBATCH * TT)      // 32768
#define CT    32                 // rows per apl1 block == scan chunk
#define NCH   (TT / CT)          // 128 chunks per batch (1024 total)

typedef short bf16x8 __attribute__((ext_vector_type(8)));
typedef float f32x4  __attribute__((ext_vector_type(4)));

__device__ __forceinline__ unsigned short f2bf(float f) {
    union { float f; unsigned int u; } v; v.f = f;
    unsigned int r = v.u + 0x7fffu + ((v.u >> 16) & 1u);   // RNE
    return (unsigned short)(r >> 16);
}

__device__ __forceinline__ float bf2f(unsigned short b) {
    union { float f; unsigned int u; } v; v.u = ((unsigned int)b) << 16;
    return v.f;
}

__device__ __forceinline__ void gload_lds16(const void* g, void* l) {
    __builtin_amdgcn_global_load_lds(
        (const __attribute__((address_space(1))) unsigned int*)g,
        (__attribute__((address_space(3))) unsigned int*)l, 16, 0, 0);
}

// pack the 8 piecewise-linear knot weights for one scalar into 4 dwords (8 bf16)
__device__ __forceinline__ uint4 apl_w_pack(float xv) {
    float t = fminf(fmaxf((xv + 1.0f) * 3.5f, 0.0f), 7.0f);
    int idx = (int)t; if (idx > 6) idx = 6;
    float frac = t - (float)idx;
    const unsigned int b0 = f2bf(1.0f - frac);
    const unsigned int b1 = f2bf(frac);
    const int q = idx >> 1;
    const bool odd = (idx & 1) != 0;
    const unsigned int vA = odd ? (b0 << 16) : (b0 | (b1 << 16));
    const unsigned int vB = odd ? b1 : 0u;
    uint4 w;
    w.x = (q == 0) ? vA : 0u;
    w.y = (q == 1) ? vA : ((q == 0) ? vB : 0u);
    w.z = (q == 2) ? vA : ((q == 1) ? vB : 0u);
    w.w = (q == 3) ? vA : ((q == 2) ? vB : 0u);
    return w;
}

// ---------------------------------------------------------------------------
// prep_tables: Vt[col][k] bf16 (256x512) from hv|zv (k=i*8+p; col<128 -> hv)
//              Ot[col][k] bf16 (64x1024) from ov (k=d*8+p)
// ---------------------------------------------------------------------------
__global__ __launch_bounds__(256) void prep_tables(
    const float* __restrict__ hv, const float* __restrict__ zv,
    const float* __restrict__ ov,
    unsigned short* __restrict__ Vt, unsigned short* __restrict__ Ot)
{
    const int b = blockIdx.x, tid = threadIdx.x;
    if (b < 512) {
        const int k = b, c = tid;
        float v = (c < 128) ? hv[(size_t)k * 128 + c] : zv[(size_t)k * 128 + (c - 128)];
        Vt[(size_t)c * 512 + k] = f2bf(v);
    } else {
        const int k = (b - 512) * 4 + (tid >> 6), c = tid & 63;
        Ot[(size_t)c * 1024 + k] = f2bf(ov[(size_t)k * 64 + c]);
    }
}

// ---------------------------------------------------------------------------
// APL1 GEMM (round-2/3 proven core): C(n, 0..255) = W(n, 0..511) x Vt^T.
// Cols 0-127 -> h_bar bf16 panel, 128-255 -> sigmoid -> z bf16 panel.
// Panel layout: hz[chunk g][col 0..127][row 0..31] bf16 (contiguous per col).
// Also emits chunk partial sums of h_bar (fp32, from accumulators).
// ---------------------------------------------------------------------------
__global__ __launch_bounds__(256) void apl1_gemm(
    const float* __restrict__ x, const unsigned short* __restrict__ Vt,
    unsigned short* __restrict__ hz,      // h panels; z panels at +NTOT*DD
    float* __restrict__ partial)          // (1024, 128)
{
    __shared__ unsigned char smem[65536];
    const int tid = threadIdx.x;
    const int wave = tid >> 6, lane = tid & 63;
    const int g = blockIdx.x;
    const int n0 = g * CT;

    // stage Vt chunk 0 into buf0
    {
        unsigned char* buf = smem + 32768;
        #pragma unroll
        for (int j = 0; j < 4; ++j) {
            const int r0 = wave * 64 + j * 16;
            const int r = r0 + (lane >> 2);
            const int ug = (lane & 3) ^ ((r >> 2) & 3);
            gload_lds16((const unsigned char*)Vt + (size_t)r * 1024 + ug * 16,
                        buf + r0 * 64);
        }
    }

    // build W (32 rows x 512 k) in LDS
    #pragma unroll
    for (int it = 0; it < 8; ++it) {
        const int n = wave + 4 * it;
        const int i = lane;
        uint4 w = apl_w_pack(x[(size_t)(n0 + n) * II + i]);
        const int up = i ^ (n & 7);
        *(uint4*)(smem + n * 1024 + up * 16) = w;
    }
    __syncthreads();

    const int colbase = wave * 64;
    f32x4 acc[2][4];
    #pragma unroll
    for (int tr = 0; tr < 2; ++tr)
        #pragma unroll
        for (int tc = 0; tc < 4; ++tc)
            acc[tr][tc] = (f32x4){0.f, 0.f, 0.f, 0.f};

    const int klane = (lane >> 4) * 8;   // 0,8,16,24

    for (int c = 0; c < 16; ++c) {
        unsigned char* cur = smem + 32768 + (c & 1) * 16384;
        if (c < 15) {
            unsigned char* nxt = smem + 32768 + ((c + 1) & 1) * 16384;
            #pragma unroll
            for (int j = 0; j < 4; ++j) {
                const int r0 = wave * 64 + j * 16;
                const int r = r0 + (lane >> 2);
                const int ug = (lane & 3) ^ ((r >> 2) & 3);
                gload_lds16((const unsigned char*)Vt + (size_t)r * 1024 + (c + 1) * 64 + ug * 16,
                            nxt + r0 * 64);
            }
        }
        bf16x8 a[2];
        const int ugA = (c * 32 + klane) >> 3;
        #pragma unroll
        for (int tr = 0; tr < 2; ++tr) {
            const int r = tr * 16 + (lane & 15);
            a[tr] = *(const bf16x8*)(smem + r * 1024 + (ugA ^ (r & 7)) * 16);
        }
        bf16x8 b[4];
        const int ugB = klane >> 3;
        #pragma unroll
        for (int tc = 0; tc < 4; ++tc) {
            const int rc = colbase + tc * 16 + (lane & 15);
            b[tc] = *(const bf16x8*)(cur + rc * 64 + (ugB ^ ((rc >> 2) & 3)) * 16);
        }
        #pragma unroll
        for (int tr = 0; tr < 2; ++tr)
            #pragma unroll
            for (int tc = 0; tc < 4; ++tc)
                acc[tr][tc] = __builtin_amdgcn_mfma_f32_16x16x32_bf16(a[tr], b[tc], acc[tr][tc], 0, 0, 0);
        __syncthreads();
    }

    // chunk partial sums of h_bar (waves 0,1 hold cols 0..127)
    if (wave < 2) {
        #pragma unroll
        for (int tc = 0; tc < 4; ++tc) {
            float s = 0.0f;
            #pragma unroll
            for (int tr = 0; tr < 2; ++tr)
                #pragma unroll
                for (int rg = 0; rg < 4; ++rg)
                    s += acc[tr][tc][rg];
            s += __shfl_xor(s, 16);
            s += __shfl_xor(s, 32);
            if ((lane >> 4) == 0)
                partial[(size_t)g * 128 + colbase + tc * 16 + lane] = s;
        }
    }

    // epilogue: bf16 panels.  C/D layout col=lane&15 (+tile), row=(lane>>4)*4+reg
    unsigned short* panh = hz + (size_t)g * (128 * CT);
    unsigned short* panz = hz + (size_t)NTOT * DD + (size_t)g * (128 * CT);
    #pragma unroll
    for (int tr = 0; tr < 2; ++tr) {
        #pragma unroll
        for (int tc = 0; tc < 4; ++tc) {
            const int col = colbase + tc * 16 + (lane & 15);
            const int r0 = tr * 16 + (lane >> 4) * 4;
            f32x4 v = acc[tr][tc];
            ushort4 p4;
            if (col < 128) {
                p4.x = f2bf(v[0]); p4.y = f2bf(v[1]);
                p4.z = f2bf(v[2]); p4.w = f2bf(v[3]);
                *(ushort4*)(panh + col * CT + r0) = p4;
            } else {
                p4.x = f2bf(1.0f / (1.0f + __expf(-v[0])));
                p4.y = f2bf(1.0f / (1.0f + __expf(-v[1])));
                p4.z = f2bf(1.0f / (1.0f + __expf(-v[2])));
                p4.w = f2bf(1.0f / (1.0f + __expf(-v[3])));
                *(ushort4*)(panz + (col - 128) * CT + r0) = p4;
            }
        }
    }
}

// ---------------------------------------------------------------------------
// Exclusive scan of chunk partials (+h0), one block per batch, LDS-resident.
// (round-3 proven)
// ---------------------------------------------------------------------------
__global__ __launch_bounds__(128) void scan_exclusive_v2(
    float* __restrict__ partial, const float* __restrict__ h0)
{
    __shared__ float s[NCH * 128];       // 64 KB
    const int b = blockIdx.x, d = threadIdx.x;
    for (int c = 0; c < NCH; ++c)
        s[c * 128 + d] = partial[((size_t)b * NCH + c) * 128 + d];
    __syncthreads();
    float run = h0[(size_t)b * 128 + d];
    for (int c = 0; c < NCH; ++c) {
        float v = s[c * 128 + d];
        s[c * 128 + d] = run;
        run += v;
    }
    __syncthreads();
    for (int c = 0; c < NCH; ++c)
        partial[((size_t)b * NCH + c) * 128 + d] = s[c * 128 + d];
}

// ---------------------------------------------------------------------------
// Fused: z-mix scan (ht) + output APL GEMM.  Block = 64 rows (2 panels).
// Phase 1 (tid<128): thread d scans 64 rows from bf16 panels (contiguous
// ushort4 loads), writes fp32 ht to d_out and bf16 ht to LDS.
// Phase 2: GEMM y = W2(64x1024) x Ot^T, W2 AND Ot double-buffered
// (1 sync per chunk), W2 built from LDS ht.
// LDS: Ot dbuf 2x8192 @0 | W2 dbuf 2x8192 @16384 | htb 64x132 shorts @32768.
// ---------------------------------------------------------------------------
__global__ __launch_bounds__(256) void fused2(
    const unsigned short* __restrict__ hz,   // h panels; z at +NTOT*DD
    const float* __restrict__ pexcl,         // (1024, 128) exclusive sums
    const unsigned short* __restrict__ Ot,   // (64, 1024) bf16
    float* __restrict__ ht_out, float* __restrict__ y)
{
    __shared__ unsigned char smem[49664];
    const int tid = threadIdx.x;
    const int wave = tid >> 6, lane = tid & 63;
    const int g = blockIdx.x;            // 64-row group = panels 2g, 2g+1
    const int n0 = g * 64;

    auto stageOt = [&](int c, int bi) {
        unsigned char* buf = smem + bi * 8192;
        #pragma unroll
        for (int j = 0; j < 2; ++j) {
            const int r0 = wave * 16 + j * 8;
            const int r = r0 + (lane >> 3);
            const int ug = (lane & 7) ^ (r & 7);
            gload_lds16((const unsigned char*)Ot + (size_t)r * 2048 + c * 128 + ug * 16,
                        buf + r0 * 128);
        }
    };

    // kick off Ot chunk-0 DMA so it overlaps the scan
    stageOt(0, 0);

    // ---- phase 1: scan -> ht (global fp32 + LDS bf16) ----
    if (tid < 128) {
        const int d = tid;
        float run = pexcl[(size_t)(2 * g) * 128 + d];
        const unsigned short* hp = hz + (size_t)(2 * g) * (128 * CT) + d * CT;
        const unsigned short* zp = hp + (size_t)NTOT * DD;
        unsigned short* htb = (unsigned short*)(smem + 32768);
        #pragma unroll
        for (int half = 0; half < 2; ++half) {
            const unsigned short* hq = hp + half * (128 * CT);
            const unsigned short* zq = zp + half * (128 * CT);
            #pragma unroll
            for (int rq = 0; rq < 8; ++rq) {
                ushort4 h4 = *(const ushort4*)(hq + rq * 4);
                ushort4 z4 = *(const ushort4*)(zq + rq * 4);
                const unsigned short* hpp = (const unsigned short*)&h4;
                const unsigned short* zpp = (const unsigned short*)&z4;
                #pragma unroll
                for (int k = 0; k < 4; ++k) {
                    const int r = half * 32 + rq * 4 + k;
                    float hb = bf2f(hpp[k]);
                    float zt = bf2f(zpp[k]);
                    run += hb;
                    float htv = (1.0f - zt) * run + zt * hb;
                    ht_out[(size_t)(n0 + r) * DD + d] = htv;
                    htb[r * 132 + d] = f2bf(htv);
                }
            }
        }
    }
    __syncthreads();   // htb ready; Ot chunk 0 staged (barrier drains DMA)

    auto buildW2 = [&](int c, int bi) {
        unsigned char* wb = smem + 16384 + bi * 8192;
        const unsigned short* htb = (const unsigned short*)(smem + 32768);
        const int n = tid >> 2, dl2 = tid & 3;
        float ha  = bf2f(htb[n * 132 + c * 8 + 2 * dl2]);
        float hbv = bf2f(htb[n * 132 + c * 8 + 2 * dl2 + 1]);
        uint4 w0 = apl_w_pack(ha);
        uint4 w1 = apl_w_pack(hbv);
        *(uint4*)(wb + n * 128 + (((2 * dl2)     ^ (n & 7)) * 16)) = w0;
        *(uint4*)(wb + n * 128 + (((2 * dl2 + 1) ^ (n & 7)) * 16)) = w1;
    };

    buildW2(0, 0);
    __syncthreads();

    const int wr = wave >> 1, wc = wave & 1;
    f32x4 acc2[2][2];
    #pragma unroll
    for (int tr = 0; tr < 2; ++tr)
        #pragma unroll
        for (int tc = 0; tc < 2; ++tc)
            acc2[tr][tc] = (f32x4){0.f, 0.f, 0.f, 0.f};

    for (int c = 0; c < 16; ++c) {
        if (c < 15) {
            stageOt(c + 1, (c + 1) & 1);
            buildW2(c + 1, (c + 1) & 1);
        }
        unsigned char* wb = smem + 16384 + (c & 1) * 8192;
        unsigned char* ob = smem + (c & 1) * 8192;
        #pragma unroll
        for (int s = 0; s < 2; ++s) {
            const int pos = s * 4 + (lane >> 4);
            bf16x8 a2[2], b2[2];
            #pragma unroll
            for (int tr = 0; tr < 2; ++tr) {
                const int r = wr * 32 + tr * 16 + (lane & 15);
                a2[tr] = *(const bf16x8*)(wb + r * 128 + ((pos ^ (r & 7)) * 16));
            }
            #pragma unroll
            for (int tc = 0; tc < 2; ++tc) {
                const int rc = wc * 32 + tc * 16 + (lane & 15);
                b2[tc] = *(const bf16x8*)(ob + rc * 128 + ((pos ^ (rc & 7)) * 16));
            }
            #pragma unroll
            for (int tr = 0; tr < 2; ++tr)
                #pragma unroll
                for (int tc = 0; tc < 2; ++tc)
                    acc2[tr][tc] = __builtin_amdgcn_mfma_f32_16x16x32_bf16(a2[tr], b2[tc], acc2[tr][tc], 0, 0, 0);
        }
        __syncthreads();
    }

    #pragma unroll
    for (int tr = 0; tr < 2; ++tr)
        #pragma unroll
        for (int tc = 0; tc < 2; ++tc) {
            const int col = wc * 32 + tc * 16 + (lane & 15);
            const int n = n0 + wr * 32 + tr * 16 + (lane >> 4) * 4;
            f32x4 v = acc2[tr][tc];
            #pragma unroll
            for (int rg = 0; rg < 4; ++rg)
                y[(size_t)(n + rg) * OO + col] = v[rg];
        }
}

// ---------------------------------------------------------------------------
extern "C" void kernel_launch(void* const* d_in, const int* in_sizes, int n_in,
                              void* d_out, int out_size, void* d_ws, size_t ws_size,
                              hipStream_t stream) {
    const float* x  = (const float*)d_in[0];   // (B,T,I)
    const float* h0 = (const float*)d_in[1];   // (B,D)
    const float* zv = (const float*)d_in[2];   // (I,P,D)
    const float* hv = (const float*)d_in[3];   // (I,P,D)
    const float* ov = (const float*)d_in[4];   // (D,P,O)

    float* y  = (float*)d_out;                           // (B,T,O)
    float* ht = (float*)d_out + (size_t)NTOT * OO;       // (B,T,D)

    float* partial = (float*)d_ws;                                   // 1024*128 f32 = 512 KB
    unsigned short* Vt = (unsigned short*)(partial + 1024 * 128);    // 256x512 bf16
    unsigned short* Ot = Vt + 256 * 512;                             // 64x1024 bf16
    unsigned short* hz = Ot + 64 * 1024;                             // 2 * NTOT*DD bf16 = 16 MB

    prep_tables<<<768, 256, 0, stream>>>(hv, zv, ov, Vt, Ot);
    apl1_gemm<<<NTOT / CT, 256, 0, stream>>>(x, Vt, hz, partial);
    scan_exclusive_v2<<<BBATCH, 128, 0, stream>>>(partial, h0);
    fused2<<<NTOT / 64, 256, 0, stream>>>(hz, partial, Ot, ht, y);
}